// Round 1
// baseline (425.594 us; speedup 1.0000x reference)
//
#include <hip/hip_runtime.h>
#include <math.h>

// Weights from the reference
#define SDF_W      7000.0f
#define EIK_W      600.0f
#define ORI_W      500.0f
#define NEAR_ORI_W 10.0f
#define GRADN_W    200.0f

// ---------------------------------------------------------------------------
// acc layout in d_ws (floats): [0]=sdf_sum [1]=eik_sum [2]=gradn_sum
//                              [3]=ori_sum [4]=near_ori_sum  (8 reserved)
// h array (|s|^2 / 2 per surface point) lives at d_ws + 256 bytes.
// ---------------------------------------------------------------------------

__global__ __launch_bounds__(256) void init_acc(float* acc) {
    if (threadIdx.x < 8) acc[threadIdx.x] = 0.0f;
}

// Small losses + precompute h[j] = 0.5*|s_j|^2
__global__ __launch_bounds__(256) void prep_small(
    const float* __restrict__ mp, const float* __restrict__ mg,
    const float* __restrict__ sp, const float* __restrict__ sn,
    float* __restrict__ h, float* __restrict__ acc, int N)
{
    int i = blockIdx.x * 256 + threadIdx.x;
    float sdf = 0.f, eik = 0.f, gn = 0.f;
    if (i < N) {
        float p = mp[i];
        sdf = p * p;
        float gx = mg[3*i], gy = mg[3*i+1], gz = mg[3*i+2];
        float nrm = sqrtf(fmaf(gx, gx, fmaf(gy, gy, gz * gz)));
        float d = nrm - 1.0f;
        eik = d * d;
        float sx = sp[3*i], sy = sp[3*i+1], sz = sp[3*i+2];
        if (h) h[i] = 0.5f * fmaf(sx, sx, fmaf(sy, sy, sz * sz));
        float nx = sn[3*i], ny = sn[3*i+1], nz = sn[3*i+2];
        float dx = gx - nx, dy = gy - ny, dz = gz - nz;
        gn = fmaf(dx, dx, fmaf(dy, dy, dz * dz));
    }
    __shared__ float red0[256], red1[256], red2[256];
    int t = threadIdx.x;
    red0[t] = sdf; red1[t] = eik; red2[t] = gn;
    __syncthreads();
    for (int off = 128; off > 0; off >>= 1) {
        if (t < off) {
            red0[t] += red0[t + off];
            red1[t] += red1[t + off];
            red2[t] += red2[t + off];
        }
        __syncthreads();
    }
    if (t == 0) {
        atomicAdd(&acc[0], red0[0]);
        atomicAdd(&acc[1], red1[0]);
        atomicAdd(&acc[2], red2[0]);
    }
}

// Brute-force 2-NN + orientation sign + relu term, fused.
// Block = 256 threads = 64 queries x 4 S-splits (split is wave-uniform).
// USE_H: g = q.s - h[j]  (3 FMA); else g = -|q-s|^2 (7 ops, ws fallback).
template<int USE_H>
__global__ __launch_bounds__(256) void nn_sign(
    const float* __restrict__ offq, const float* __restrict__ nearq,
    const float* __restrict__ surf, const float* __restrict__ norms,
    const float* __restrict__ h,
    const float* __restrict__ nmpred, const float* __restrict__ nppred,
    float* __restrict__ acc, int S, int Qoff)
{
    const int t = threadIdx.x;
    const int qi = t & 63;
    // force wave-uniform so surface loads become broadcast/scalar loads
    const int split = __builtin_amdgcn_readfirstlane(t >> 6);   // 0..3
    const int gq = blockIdx.x * 64 + qi;
    const bool nearSet = (blockIdx.x * 64 >= Qoff);             // block-uniform
    const float* qbase = nearSet ? (nearq + 3 * (gq - Qoff)) : (offq + 3 * gq);
    const float qx = qbase[0], qy = qbase[1], qz = qbase[2];

    const int chunk = S >> 2;
    const int j0 = split * chunk;
    const int jend = (split == 3) ? S : (j0 + chunk);

    float m1 = -3.0e38f, m2 = -3.0e38f;   // running top-2 of g (max = nearest)
    int   i1 = 0,        i2 = 0;

    #pragma unroll 4
    for (int j = j0; j < jend; ++j) {
        float sx = surf[3*j], sy = surf[3*j+1], sz = surf[3*j+2];
        float g;
        if (USE_H) {
            g = fmaf(qx, sx, fmaf(qy, sy, fmaf(qz, sz, -h[j])));
        } else {
            float dx = qx - sx, dy = qy - sy, dz = qz - sz;
            g = -fmaf(dx, dx, fmaf(dy, dy, dz * dz));
        }
        bool b1 = g > m1;     // strict >: keeps earliest index on ties (top_k stable)
        bool b2 = g > m2;
        float t2 = b2 ? g : m2;
        int   u2 = b2 ? j : i2;
        m2 = b1 ? m1 : t2;
        i2 = b1 ? i1 : u2;
        m1 = b1 ? g  : m1;
        i1 = b1 ? j  : i1;
    }

    __shared__ float sm1[256], sm2[256];
    __shared__ int   si1[256], si2[256];
    __shared__ float red[256];
    sm1[t] = m1; sm2[t] = m2; si1[t] = i1; si2[t] = i2;
    __syncthreads();

    float term = 0.f;
    if (t < 64) {
        // merge the 4 split partials (thread t == query qi, its own split-0 partial)
        float M1 = sm1[t], M2 = sm2[t];
        int   I1 = si1[t], I2 = si2[t];
        #pragma unroll
        for (int s2 = 1; s2 < 4; ++s2) {
            int o = t + 64 * s2;
            float a1 = sm1[o], a2 = sm2[o];
            int   j1 = si1[o], j2 = si2[o];
            if (a1 > M1)      { M2 = M1; I2 = I1; M1 = a1; I1 = j1; }
            else if (a1 > M2) { M2 = a1; I2 = j1; }
            if (a2 > M2)      { M2 = a2; I2 = j2; }   // a2 <= a1 <= M1 here
        }
        // gather the two neighbors, compute sign(mean dot)
        float p1x = surf[3*I1], p1y = surf[3*I1+1], p1z = surf[3*I1+2];
        float n1x = norms[3*I1], n1y = norms[3*I1+1], n1z = norms[3*I1+2];
        float p2x = surf[3*I2], p2y = surf[3*I2+1], p2z = surf[3*I2+2];
        float n2x = norms[3*I2], n2y = norms[3*I2+1], n2z = norms[3*I2+2];
        float dot1 = (qx - p1x) * n1x + (qy - p1y) * n1y + (qz - p1z) * n1z;
        float dot2 = (qx - p2x) * n2x + (qy - p2y) * n2y + (qz - p2z) * n2z;
        float msum = dot1 + dot2;                     // sign(mean) == sign(sum)
        float sgn  = (msum > 0.f) ? 1.f : ((msum < 0.f) ? -1.f : 0.f);
        float pred = nearSet ? nppred[gq - Qoff] : nmpred[gq];
        term = fmaxf(0.f, -pred * sgn);
    }
    red[t] = term;
    __syncthreads();
    for (int off = 128; off > 0; off >>= 1) {
        if (t < off) red[t] += red[t + off];
        __syncthreads();
    }
    if (t == 0) atomicAdd(&acc[nearSet ? 4 : 3], red[0]);
}

__global__ void final_k(const float* __restrict__ acc, float* __restrict__ out,
                        int N, int Qoff, int Qnear)
{
    if (threadIdx.x == 0) {
        float sdf  = acc[0] / (float)N;
        float eik  = acc[1] / (float)N;
        float gn   = acc[2] / (3.0f * (float)N);
        float ori  = acc[3] / (float)Qoff;
        float nori = acc[4] / (float)Qnear;
        out[0] = SDF_W * sdf + EIK_W * eik + ORI_W * ori
               + NEAR_ORI_W * nori + GRADN_W * gn;
        out[1] = sdf;
        out[2] = eik;
        out[3] = ori;
        out[4] = nori;
        out[5] = gn;
    }
}

extern "C" void kernel_launch(void* const* d_in, const int* in_sizes, int n_in,
                              void* d_out, int out_size, void* d_ws, size_t ws_size,
                              hipStream_t stream)
{
    const float* mp    = (const float*)d_in[0];  // manifold_pred      [N,1]
    const float* mg    = (const float*)d_in[1];  // manifold_grad      [N,3]
    const float* nmp   = (const float*)d_in[2];  // nonmanifold_pred   [N,1]
    const float* npp   = (const float*)d_in[3];  // near_points_pred   [N,1]
    const float* sp    = (const float*)d_in[4];  // surface_points     [S,3]
    const float* sn    = (const float*)d_in[5];  // surface_normals    [S,3]
    const float* offp  = (const float*)d_in[6];  // off_surface_points [Q,3]
    const float* nearp = (const float*)d_in[7];  // near_points        [Q,3]
    float* out = (float*)d_out;

    const int N     = in_sizes[0];
    const int S     = in_sizes[4] / 3;
    const int Qoff  = in_sizes[2];
    const int Qnear = in_sizes[3];

    float* acc = (float*)d_ws;
    float* h   = (float*)((char*)d_ws + 256);
    const bool useH = ws_size >= (size_t)(256 + 4 * (size_t)S);

    init_acc<<<1, 256, 0, stream>>>(acc);
    prep_small<<<(N + 255) / 256, 256, 0, stream>>>(mp, mg, sp, sn,
                                                    useH ? h : nullptr, acc, N);
    const int QT = Qoff + Qnear;            // 32768 -> 512 blocks
    const int nnBlocks = QT / 64;
    if (useH) {
        nn_sign<1><<<nnBlocks, 256, 0, stream>>>(offp, nearp, sp, sn, h,
                                                 nmp, npp, acc, S, Qoff);
    } else {
        nn_sign<0><<<nnBlocks, 256, 0, stream>>>(offp, nearp, sp, sn, nullptr,
                                                 nmp, npp, acc, S, Qoff);
    }
    final_k<<<1, 64, 0, stream>>>(acc, out, N, Qoff, Qnear);
}

// Round 2
// 252.768 us; speedup vs baseline: 1.6837x; 1.6837x over previous
//
#include <hip/hip_runtime.h>
#include <math.h>

// Weights from the reference
#define SDF_W      7000.0f
#define EIK_W      600.0f
#define ORI_W      500.0f
#define NEAR_ORI_W 10.0f
#define GRADN_W    200.0f

// d_ws float layout:
//   [0 .. 511]   nn block partials (ori: blocks [0,nbOff), nori: [nbOff, nbOff+nbNear))
//   [512..575]   sdf partials   (prep blocks)
//   [576..639]   eik partials
//   [640..703]   gradn partials
#define WS_NN    0
#define WS_SDF   512
#define WS_EIK   576
#define WS_GN    640

// ---------------------------------------------------------------------------
// Small losses, per-block partials (no atomics, no init kernel needed)
// ---------------------------------------------------------------------------
__global__ __launch_bounds__(256) void prep_small(
    const float* __restrict__ mp, const float* __restrict__ mg,
    const float* __restrict__ sn, float* __restrict__ ws, int N)
{
    int i = blockIdx.x * 256 + threadIdx.x;
    float sdf = 0.f, eik = 0.f, gn = 0.f;
    if (i < N) {
        float p = mp[i];
        sdf = p * p;
        float gx = mg[3*i], gy = mg[3*i+1], gz = mg[3*i+2];
        float nrm = sqrtf(fmaf(gx, gx, fmaf(gy, gy, gz * gz)));
        float d = nrm - 1.0f;
        eik = d * d;
        float nx = sn[3*i], ny = sn[3*i+1], nz = sn[3*i+2];
        float dx = gx - nx, dy = gy - ny, dz = gz - nz;
        gn = fmaf(dx, dx, fmaf(dy, dy, dz * dz));
    }
    __shared__ float red0[256], red1[256], red2[256];
    int t = threadIdx.x;
    red0[t] = sdf; red1[t] = eik; red2[t] = gn;
    __syncthreads();
    for (int off = 128; off > 0; off >>= 1) {
        if (t < off) {
            red0[t] += red0[t + off];
            red1[t] += red1[t + off];
            red2[t] += red2[t + off];
        }
        __syncthreads();
    }
    if (t == 0) {
        ws[WS_SDF + blockIdx.x] = red0[0];
        ws[WS_EIK + blockIdx.x] = red1[0];
        ws[WS_GN  + blockIdx.x] = red2[0];
    }
}

// ---------------------------------------------------------------------------
// Fused brute-force 2-NN + orientation sign + relu term.
// Block = 256 threads = 64 queries x 4 wave-splits of S.
// Surface points staged into LDS as float4 (x,y,z,-|s|^2/2); scan reads are
// wave-uniform ds_read_b128 (broadcast, conflict-free).
// g = q.s - |s|^2/2 is monotone-equivalent to -d2/2 (same argmax set).
// ---------------------------------------------------------------------------
#define TILE 4096

__global__ __launch_bounds__(256) void nn_sign(
    const float* __restrict__ offq, const float* __restrict__ nearq,
    const float* __restrict__ surf, const float* __restrict__ norms,
    const float* __restrict__ nmpred, const float* __restrict__ nppred,
    float* __restrict__ ws, int S, int Qoff, int Qnear, int nbOff)
{
    __shared__ float4 tile[TILE];                   // 64 KB
    __shared__ float sm1[256], sm2[256], red[256];
    __shared__ int   si1[256], si2[256];

    const int t  = threadIdx.x;
    const int qi = t & 63;
    const int split = __builtin_amdgcn_readfirstlane(t >> 6);   // 0..3, wave-uniform
    const bool nearSet = (blockIdx.x >= nbOff);                 // block-uniform
    const int  qb   = nearSet ? (blockIdx.x - nbOff) : blockIdx.x;
    const int  Qcnt = nearSet ? Qnear : Qoff;
    const int  gq   = qb * 64 + qi;
    const bool qvalid = (gq < Qcnt);
    const int  cq   = qvalid ? gq : 0;
    const float* qbase = (nearSet ? nearq : offq) + 3 * cq;
    const float qx = qbase[0], qy = qbase[1], qz = qbase[2];

    float m1 = -3.0e38f, m2 = -3.0e38f;   // running top-2 of g (max = nearest)
    int   i1 = 0,        i2 = 0;

    const int nTiles = (S + TILE - 1) / TILE;
    for (int tt = 0; tt < nTiles; ++tt) {
        const int base = tt * TILE;
        __syncthreads();                            // previous scan done
        // ---- stage 4096 points cooperatively (16/thread, lane-contiguous) ----
        #pragma unroll
        for (int r = 0; r < TILE / 256; ++r) {
            int li = t + 256 * r;
            int p  = base + li;
            float sx = 0.f, sy = 0.f, sz = 0.f, nh = -3.0e38f;
            if (p < S) {
                sx = surf[3*p]; sy = surf[3*p+1]; sz = surf[3*p+2];
                nh = -0.5f * fmaf(sx, sx, fmaf(sy, sy, sz * sz));
            }
            tile[li] = make_float4(sx, sy, sz, nh);
        }
        __syncthreads();
        // ---- scan: wave `split` covers its quarter of the tile ----
        const int lo    = split << 10;              // *1024
        const int jbase = base + lo;
        const float4* __restrict__ tp = tile + lo;
        #pragma unroll 8
        for (int o = 0; o < 1024; ++o) {
            float4 s4 = tp[o];                      // ds_read_b128, broadcast
            float g = fmaf(qx, s4.x, fmaf(qy, s4.y, fmaf(qz, s4.z, s4.w)));
            int j = jbase + o;
            bool b1 = g > m1;      // strict >: earliest index wins ties (top_k stable)
            bool b2 = g > m2;
            float t2 = b2 ? g : m2;
            int   u2 = b2 ? j : i2;
            m2 = b1 ? m1 : t2;
            i2 = b1 ? i1 : u2;
            m1 = b1 ? g  : m1;
            i1 = b1 ? j  : i1;
        }
    }

    sm1[t] = m1; sm2[t] = m2; si1[t] = i1; si2[t] = i2;
    __syncthreads();

    float term = 0.f;
    if (t < 64) {
        // merge the 4 split partials (ascending split order keeps low-j tie-break)
        float M1 = sm1[t], M2 = sm2[t];
        int   I1 = si1[t], I2 = si2[t];
        #pragma unroll
        for (int s2 = 1; s2 < 4; ++s2) {
            int o = t + 64 * s2;
            float a1 = sm1[o], a2 = sm2[o];
            int   j1 = si1[o], j2 = si2[o];
            if (a1 > M1)      { M2 = M1; I2 = I1; M1 = a1; I1 = j1; }
            else if (a1 > M2) { M2 = a1; I2 = j1; }
            if (a2 > M2)      { M2 = a2; I2 = j2; }   // a2 <= a1 <= M1 here
        }
        // gather the two neighbors, sign(mean dot) == sign(sum dot)
        float p1x = surf[3*I1], p1y = surf[3*I1+1], p1z = surf[3*I1+2];
        float n1x = norms[3*I1], n1y = norms[3*I1+1], n1z = norms[3*I1+2];
        float p2x = surf[3*I2], p2y = surf[3*I2+1], p2z = surf[3*I2+2];
        float n2x = norms[3*I2], n2y = norms[3*I2+1], n2z = norms[3*I2+2];
        float dot1 = (qx - p1x) * n1x + (qy - p1y) * n1y + (qz - p1z) * n1z;
        float dot2 = (qx - p2x) * n2x + (qy - p2y) * n2y + (qz - p2z) * n2z;
        float msum = dot1 + dot2;
        float sgn  = (msum > 0.f) ? 1.f : ((msum < 0.f) ? -1.f : 0.f);
        float pred = nearSet ? nppred[cq] : nmpred[cq];
        term = qvalid ? fmaxf(0.f, -pred * sgn) : 0.f;
    }
    red[t] = term;
    __syncthreads();
    for (int off = 128; off > 0; off >>= 1) {
        if (t < off) red[t] += red[t + off];
        __syncthreads();
    }
    if (t == 0) ws[WS_NN + blockIdx.x] = red[0];
}

// ---------------------------------------------------------------------------
// Final reduction of all partials + weighted total
// ---------------------------------------------------------------------------
__global__ __launch_bounds__(256) void final_k(
    const float* __restrict__ ws, float* __restrict__ out,
    int N, int prepBlocks, int nbOff, int nbNear, int Qoff, int Qnear)
{
    __shared__ float r0[256], r1[256], r2[256], r3[256], r4[256];
    int t = threadIdx.x;
    float ori = 0.f, nori = 0.f, sdf = 0.f, eik = 0.f, gn = 0.f;
    for (int i = t; i < nbOff;  i += 256) ori  += ws[WS_NN + i];
    for (int i = t; i < nbNear; i += 256) nori += ws[WS_NN + nbOff + i];
    for (int i = t; i < prepBlocks; i += 256) {
        sdf += ws[WS_SDF + i];
        eik += ws[WS_EIK + i];
        gn  += ws[WS_GN  + i];
    }
    r0[t] = ori; r1[t] = nori; r2[t] = sdf; r3[t] = eik; r4[t] = gn;
    __syncthreads();
    for (int off = 128; off > 0; off >>= 1) {
        if (t < off) {
            r0[t] += r0[t + off];
            r1[t] += r1[t + off];
            r2[t] += r2[t + off];
            r3[t] += r3[t + off];
            r4[t] += r4[t + off];
        }
        __syncthreads();
    }
    if (t == 0) {
        float sdfm  = r2[0] / (float)N;
        float eikm  = r3[0] / (float)N;
        float gnm   = r4[0] / (3.0f * (float)N);
        float orim  = r0[0] / (float)Qoff;
        float norim = r1[0] / (float)Qnear;
        out[0] = SDF_W * sdfm + EIK_W * eikm + ORI_W * orim
               + NEAR_ORI_W * norim + GRADN_W * gnm;
        out[1] = sdfm;
        out[2] = eikm;
        out[3] = orim;
        out[4] = norim;
        out[5] = gnm;
    }
}

extern "C" void kernel_launch(void* const* d_in, const int* in_sizes, int n_in,
                              void* d_out, int out_size, void* d_ws, size_t ws_size,
                              hipStream_t stream)
{
    const float* mp    = (const float*)d_in[0];  // manifold_pred      [N,1]
    const float* mg    = (const float*)d_in[1];  // manifold_grad      [N,3]
    const float* nmp   = (const float*)d_in[2];  // nonmanifold_pred   [N,1]
    const float* npp   = (const float*)d_in[3];  // near_points_pred   [N,1]
    const float* sp    = (const float*)d_in[4];  // surface_points     [S,3]
    const float* sn    = (const float*)d_in[5];  // surface_normals    [S,3]
    const float* offp  = (const float*)d_in[6];  // off_surface_points [Q,3]
    const float* nearp = (const float*)d_in[7];  // near_points        [Q,3]
    float* out = (float*)d_out;

    const int N     = in_sizes[0];
    const int S     = in_sizes[4] / 3;
    const int Qoff  = in_sizes[2];
    const int Qnear = in_sizes[3];

    float* ws = (float*)d_ws;

    const int prepBlocks = (N + 255) / 256;
    const int nbOff  = (Qoff  + 63) / 64;
    const int nbNear = (Qnear + 63) / 64;

    prep_small<<<prepBlocks, 256, 0, stream>>>(mp, mg, sn, ws, N);
    nn_sign<<<nbOff + nbNear, 256, 0, stream>>>(offp, nearp, sp, sn,
                                                nmp, npp, ws, S, Qoff, Qnear, nbOff);
    final_k<<<1, 256, 0, stream>>>(ws, out, N, prepBlocks, nbOff, nbNear, Qoff, Qnear);
}

// Round 3
// 151.535 us; speedup vs baseline: 2.8086x; 1.6681x over previous
//
#include <hip/hip_runtime.h>
#include <math.h>

#define SDF_W      7000.0f
#define EIK_W      600.0f
#define ORI_W      500.0f
#define NEAR_ORI_W 10.0f
#define GRADN_W    200.0f

#define TILE   2048          // points per LDS tile (32 KB of float4)
#define NWAVE  8             // 512-thread blocks
#define CHK    64            // chunk granularity for index recovery
#define WS_STRIDE 512        // per-array stride (floats) for block partials
#define WS_REC 4096          // float offset of per-query records

// ws float layout:
//   [k*512 .. k*512+RB) : recover-block partials, k = 0:ori 1:nori 2:sdf 3:eik 4:gn
//   [4096 ...)          : records, float4 per (query, S-half): {M1, M2, c1, c2}

__device__ __forceinline__ float neg_half_norm2(float sx, float sy, float sz) {
    return -0.5f * fmaf(sx, sx, fmaf(sy, sy, sz * sz));
}
// Deterministic score; must be bit-identical between nn_scan and recover_k.
__device__ __forceinline__ float score(float qx, float qy, float qz,
                                       float sx, float sy, float sz, float nh) {
    return fmaf(qx, sx, fmaf(qy, sy, fmaf(qz, sz, nh)));
}

// ---------------------------------------------------------------------------
// Hot kernel: top-2 score values per (query, S-half) with chunk ids.
// No index tracking in the inner loop: M2 = max(M2, min(g,M1)); M1 = max(M1,g).
// 2 queries per lane; 8 waves split the tile; 2 blocks split S.
// ---------------------------------------------------------------------------
__global__ __launch_bounds__(512) void nn_scan(
    const float* __restrict__ offq, const float* __restrict__ nearq,
    const float* __restrict__ surf,
    float* __restrict__ ws, int S, int Qoff, int QT)
{
    __shared__ float4 tile[TILE];                 // 32 KB; reused for merge recs
    const int t    = threadIdx.x;
    const int lane = t & 63;
    const int wv   = __builtin_amdgcn_readfirstlane(t >> 6);   // 0..7

    const int qgroup = blockIdx.x >> 1;
    const int shalf  = blockIdx.x & 1;

    const int halfLen = (((S + 1) / 2) + (CHK - 1)) & ~(CHK - 1);
    const int sb = shalf ? (halfLen < S ? halfLen : S) : 0;
    const int se = shalf ? S : (halfLen < S ? halfLen : S);

    // two queries per lane
    const int qA = qgroup * 128 + lane;
    const int qB = qA + 64;
    float qAx = 0.f, qAy = 0.f, qAz = 0.f, qBx = 0.f, qBy = 0.f, qBz = 0.f;
    if (qA < QT) {
        const float* p = (qA < Qoff) ? (offq + 3 * qA) : (nearq + 3 * (qA - Qoff));
        qAx = p[0]; qAy = p[1]; qAz = p[2];
    }
    if (qB < QT) {
        const float* p = (qB < Qoff) ? (offq + 3 * qB) : (nearq + 3 * (qB - Qoff));
        qBx = p[0]; qBy = p[1]; qBz = p[2];
    }

    float M1a = -3.0e38f, M2a = -3.0e38f, M1b = -3.0e38f, M2b = -3.0e38f;
    float P1a = M1a, P2a = M2a, P1b = M1b, P2b = M2b;
    int c1a = 0, c2a = 0, c1b = 0, c2b = 0;

    for (int base = sb; base < se; base += TILE) {
        __syncthreads();
        // ---- stage 2048 points (4 per thread) as (x,y,z,-|s|^2/2) ----
        {
            int p0 = base + t * 4;
            if (p0 + 4 <= se) {
                const float4* g4 = (const float4*)(surf + 3 * p0);   // 48B aligned
                float4 r0 = g4[0], r1 = g4[1], r2 = g4[2];
                tile[t*4+0] = make_float4(r0.x, r0.y, r0.z, neg_half_norm2(r0.x, r0.y, r0.z));
                tile[t*4+1] = make_float4(r0.w, r1.x, r1.y, neg_half_norm2(r0.w, r1.x, r1.y));
                tile[t*4+2] = make_float4(r1.z, r1.w, r2.x, neg_half_norm2(r1.z, r1.w, r2.x));
                tile[t*4+3] = make_float4(r2.y, r2.z, r2.w, neg_half_norm2(r2.y, r2.z, r2.w));
            } else {
                #pragma unroll
                for (int k = 0; k < 4; ++k) {
                    int p = p0 + k;
                    if (p < se) {
                        float sx = surf[3*p], sy = surf[3*p+1], sz = surf[3*p+2];
                        tile[t*4+k] = make_float4(sx, sy, sz, neg_half_norm2(sx, sy, sz));
                    } else {
                        tile[t*4+k] = make_float4(0.f, 0.f, 0.f, -3.0e38f);
                    }
                }
            }
        }
        __syncthreads();
        // ---- scan: wave wv covers 256 pts = 4 chunks of 64 ----
        const int lo = wv * (TILE / NWAVE);
        const float4* tp = tile + lo;
        const int ccbase = (base + lo) >> 6;                  // wave-uniform
        #pragma unroll 1
        for (int c4 = 0; c4 < (TILE / NWAVE) / CHK; ++c4) {
            const float4* cp = tp + c4 * CHK;
            #pragma unroll 8
            for (int o = 0; o < CHK; ++o) {
                float4 s4 = cp[o];                            // broadcast b128
                float ga = score(qAx, qAy, qAz, s4.x, s4.y, s4.z, s4.w);
                float ta = fminf(ga, M1a);
                M2a = fmaxf(M2a, ta);
                M1a = fmaxf(M1a, ga);
                float gb = score(qBx, qBy, qBz, s4.x, s4.y, s4.z, s4.w);
                float tb = fminf(gb, M1b);
                M2b = fmaxf(M2b, tb);
                M1b = fmaxf(M1b, gb);
            }
            int cid = ccbase + c4;
            c1a = (M1a != P1a) ? cid : c1a;  P1a = M1a;
            c2a = (M2a != P2a) ? cid : c2a;  P2a = M2a;
            c1b = (M1b != P1b) ? cid : c1b;  P1b = M1b;
            c2b = (M2b != P2b) ? cid : c2b;  P2b = M2b;
        }
    }

    // ---- merge 8 wave-partials per query, write record to ws ----
    __syncthreads();
    float4* rec = tile;                                       // reuse LDS
    rec[wv * 128 + lane]      = make_float4(M1a, M2a, __int_as_float(c1a), __int_as_float(c2a));
    rec[wv * 128 + 64 + lane] = make_float4(M1b, M2b, __int_as_float(c1b), __int_as_float(c2b));
    __syncthreads();
    if (t < 128) {
        float4 r = rec[t];
        float M1 = r.x, M2 = r.y;
        int c1 = __float_as_int(r.z), c2 = __float_as_int(r.w);
        #pragma unroll
        for (int w = 1; w < NWAVE; ++w) {
            float4 a = rec[w * 128 + t];
            float a1 = a.x, a2 = a.y;
            int ac1 = __float_as_int(a.z), ac2 = __float_as_int(a.w);
            if (a1 > M1)      { M2 = M1; c2 = c1; M1 = a1; c1 = ac1; }
            else if (a1 > M2) { M2 = a1; c2 = ac1; }
            if (a2 > M2)      { M2 = a2; c2 = ac2; }
        }
        int gq = qgroup * 128 + t;
        if (gq < QT) {
            ((float4*)(ws + WS_REC))[gq * 2 + shalf] =
                make_float4(M1, M2, __int_as_float(c1), __int_as_float(c2));
        }
    }
}

// ---------------------------------------------------------------------------
// Index recovery: rescan the 2 tracked chunks for bit-exact g == M match.
// ---------------------------------------------------------------------------
__device__ __forceinline__ int find_first(const float* __restrict__ surf, int S,
                                          int c, float qx, float qy, float qz,
                                          float target, int exclude)
{
    int j0 = c * CHK;
    int j1 = j0 + CHK; if (j1 > S) j1 = S;
    if (j1 - j0 == CHK) {
        const float4* g4 = (const float4*)(surf + 3 * j0);    // 768B aligned
        int found = -1;
        #pragma unroll 1
        for (int b = 0; b < CHK / 16 && found < 0; ++b) {
            float4 raw[12];
            #pragma unroll
            for (int k = 0; k < 12; ++k) raw[k] = g4[b * 12 + k];
            const float* f = (const float*)raw;
            #pragma unroll
            for (int p = 0; p < 16; ++p) {
                float sx = f[3*p], sy = f[3*p+1], sz = f[3*p+2];
                float g = score(qx, qy, qz, sx, sy, sz, neg_half_norm2(sx, sy, sz));
                int j = j0 + b * 16 + p;
                if (found < 0 && g == target && j != exclude) found = j;
            }
        }
        return found;
    }
    for (int j = j0; j < j1; ++j) {
        float sx = surf[3*j], sy = surf[3*j+1], sz = surf[3*j+2];
        float g = score(qx, qy, qz, sx, sy, sz, neg_half_norm2(sx, sy, sz));
        if (g == target && j != exclude) return j;
    }
    return -1;
}

__global__ __launch_bounds__(128) void recover_k(
    const float* __restrict__ offq, const float* __restrict__ nearq,
    const float* __restrict__ surf, const float* __restrict__ norms,
    const float* __restrict__ nmpred, const float* __restrict__ nppred,
    const float* __restrict__ mp, const float* __restrict__ mg,
    const float* __restrict__ sn,
    float* __restrict__ ws, int S, int Qoff, int QT, int N)
{
    const int t = threadIdx.x;
    const int q = blockIdx.x * 128 + t;

    float termOri = 0.f, termNori = 0.f;
    if (q < QT) {
        const float4* recs = (const float4*)(ws + WS_REC);
        float4 r0 = recs[q * 2 + 0], r1 = recs[q * 2 + 1];
        float M1 = r0.x, M2 = r0.y;
        int c1 = __float_as_int(r0.z), c2 = __float_as_int(r0.w);
        {
            float a1 = r1.x, a2 = r1.y;
            int ac1 = __float_as_int(r1.z), ac2 = __float_as_int(r1.w);
            if (a1 > M1)      { M2 = M1; c2 = c1; M1 = a1; c1 = ac1; }
            else if (a1 > M2) { M2 = a1; c2 = ac1; }
            if (a2 > M2)      { M2 = a2; c2 = ac2; }
        }
        bool isNear = (q >= Qoff);
        const float* qp = isNear ? (nearq + 3 * (q - Qoff)) : (offq + 3 * q);
        float qx = qp[0], qy = qp[1], qz = qp[2];

        int I1 = find_first(surf, S, c1, qx, qy, qz, M1, -1);
        if (I1 < 0) I1 = 0;
        int I2 = find_first(surf, S, c2, qx, qy, qz, M2, I1);
        if (I2 < 0) I2 = (I1 == 0 && S > 1) ? 1 : 0;

        float d1 = (qx - surf[3*I1]) * norms[3*I1]
                 + (qy - surf[3*I1+1]) * norms[3*I1+1]
                 + (qz - surf[3*I1+2]) * norms[3*I1+2];
        float d2 = (qx - surf[3*I2]) * norms[3*I2]
                 + (qy - surf[3*I2+1]) * norms[3*I2+1]
                 + (qz - surf[3*I2+2]) * norms[3*I2+2];
        float ms = d1 + d2;                                   // sign(mean)==sign(sum)
        float sgn = (ms > 0.f) ? 1.f : ((ms < 0.f) ? -1.f : 0.f);
        float pred = isNear ? nppred[q - Qoff] : nmpred[q];
        float term = fmaxf(0.f, -pred * sgn);
        termOri  = isNear ? 0.f : term;
        termNori = isNear ? term : 0.f;
    }

    // fused prep (small losses)
    float sdf = 0.f, eik = 0.f, gn = 0.f;
    for (int i = q; i < N; i += QT) {
        float p = mp[i];
        sdf += p * p;
        float gx = mg[3*i], gy = mg[3*i+1], gz = mg[3*i+2];
        float nrm = sqrtf(fmaf(gx, gx, fmaf(gy, gy, gz * gz)));
        float d = nrm - 1.0f;
        eik += d * d;
        float nx = sn[3*i], ny = sn[3*i+1], nz = sn[3*i+2];
        float dx = gx - nx, dy = gy - ny, dz = gz - nz;
        gn += fmaf(dx, dx, fmaf(dy, dy, dz * dz));
    }

    __shared__ float red[5][128];
    red[0][t] = termOri; red[1][t] = termNori;
    red[2][t] = sdf;     red[3][t] = eik;      red[4][t] = gn;
    __syncthreads();
    for (int off = 64; off > 0; off >>= 1) {
        if (t < off) {
            #pragma unroll
            for (int k = 0; k < 5; ++k) red[k][t] += red[k][t + off];
        }
        __syncthreads();
    }
    if (t == 0) {
        #pragma unroll
        for (int k = 0; k < 5; ++k) ws[k * WS_STRIDE + blockIdx.x] = red[k][0];
    }
}

// ---------------------------------------------------------------------------
__global__ __launch_bounds__(256) void final_k(
    const float* __restrict__ ws, float* __restrict__ out,
    int N, int RB, int Qoff, int Qnear)
{
    __shared__ float r[5][256];
    int t = threadIdx.x;
    float s[5] = {0.f, 0.f, 0.f, 0.f, 0.f};
    for (int i = t; i < RB; i += 256) {
        #pragma unroll
        for (int k = 0; k < 5; ++k) s[k] += ws[k * WS_STRIDE + i];
    }
    #pragma unroll
    for (int k = 0; k < 5; ++k) r[k][t] = s[k];
    __syncthreads();
    for (int off = 128; off > 0; off >>= 1) {
        if (t < off) {
            #pragma unroll
            for (int k = 0; k < 5; ++k) r[k][t] += r[k][t + off];
        }
        __syncthreads();
    }
    if (t == 0) {
        float orim  = r[0][0] / (float)Qoff;
        float norim = r[1][0] / (float)Qnear;
        float sdfm  = r[2][0] / (float)N;
        float eikm  = r[3][0] / (float)N;
        float gnm   = r[4][0] / (3.0f * (float)N);
        out[0] = SDF_W * sdfm + EIK_W * eikm + ORI_W * orim
               + NEAR_ORI_W * norim + GRADN_W * gnm;
        out[1] = sdfm;
        out[2] = eikm;
        out[3] = orim;
        out[4] = norim;
        out[5] = gnm;
    }
}

extern "C" void kernel_launch(void* const* d_in, const int* in_sizes, int n_in,
                              void* d_out, int out_size, void* d_ws, size_t ws_size,
                              hipStream_t stream)
{
    const float* mp    = (const float*)d_in[0];  // manifold_pred      [N,1]
    const float* mg    = (const float*)d_in[1];  // manifold_grad      [N,3]
    const float* nmp   = (const float*)d_in[2];  // nonmanifold_pred   [N,1]
    const float* npp   = (const float*)d_in[3];  // near_points_pred   [N,1]
    const float* sp    = (const float*)d_in[4];  // surface_points     [S,3]
    const float* sn    = (const float*)d_in[5];  // surface_normals    [S,3]
    const float* offp  = (const float*)d_in[6];  // off_surface_points [Q,3]
    const float* nearp = (const float*)d_in[7];  // near_points        [Q,3]
    float* out = (float*)d_out;

    const int N     = in_sizes[0];
    const int S     = in_sizes[4] / 3;
    const int Qoff  = in_sizes[2];
    const int Qnear = in_sizes[3];
    const int QT    = Qoff + Qnear;

    float* ws = (float*)d_ws;

    const int qgroups = (QT + 127) / 128;
    const int RB      = (QT + 127) / 128;

    nn_scan<<<qgroups * 2, 512, 0, stream>>>(offp, nearp, sp, ws, S, Qoff, QT);
    recover_k<<<RB, 128, 0, stream>>>(offp, nearp, sp, sn, nmp, npp,
                                      mp, mg, sn, ws, S, Qoff, QT, N);
    final_k<<<1, 256, 0, stream>>>(ws, out, N, RB, Qoff, Qnear);
}